// Round 6
// baseline (291.620 us; speedup 1.0000x reference)
//
#include <hip/hip_runtime.h>

// B=16, C=256, H=W=64 -> N=4096, NH=4, HD=64, G=32 (8 ch/group), K=256
// ALL inputs and d_out are FP32. Internal: bf16 operands + fp32 acc.
// qkv rows: o in [0,768): q=[0,256), k=[256,512), v=[512,768)
// Workspace:
//   qkv  : (o, b*N + n) 768 x 65536 bf16 = 100,663,296 B at +0
//   ctx  : (b*4+h,e,d)  64 x 64 x 64 f32 =   1,048,576 B at +100663296
//   scsh : (b,c) float2                  =      32,768 B at +101711872
//   qst  : (o,b) float2 256x16           =      32,768 B at +101744640
//   wbf  : qkv_w bf16 768x256            =     393,216 B at +101777408
//   pbuf : (row,ntile) float2 256x512    =   1,048,576 B at +102170624
//   W2   : (b,o,c') 16x256x256 bf16 (2MB) reuses dead k-rows (+33554432)
// Pipeline: gn_stats -> wcast -> gemm1(GN fused, q-stats fused, m-fastest)
//           -> qstats_reduce -> ctx_mfma(k-softmax fused) -> w2
//           -> gemm2(q-softmax fused, m-fastest)

typedef __bf16 bf16x8 __attribute__((ext_vector_type(8)));
typedef __bf16 bf16x4 __attribute__((ext_vector_type(4)));
typedef float  f32x4  __attribute__((ext_vector_type(4)));

__device__ __forceinline__ float wave_red_sum(float v) {
#pragma unroll
    for (int off = 32; off > 0; off >>= 1) v += __shfl_xor(v, off, 64);
    return v;
}
__device__ __forceinline__ float wave_red_max(float v) {
#pragma unroll
    for (int off = 32; off > 0; off >>= 1) v = fmaxf(v, __shfl_xor(v, off, 64));
    return v;
}

// ---------------------------------------------------------------------------
// GroupNorm stats -> per-channel (sc, sh); grid 512 = (b16 x g32), block 256
// ---------------------------------------------------------------------------
__global__ __launch_bounds__(256)
void gn_stats_kernel(const float* __restrict__ x, const float* __restrict__ gw,
                     const float* __restrict__ gb, float2* __restrict__ scsh)
{
    const int blk = blockIdx.x;
    const int b = blk >> 5, g = blk & 31;
    const int tid = threadIdx.x;
    const int lane = tid & 63, wid = tid >> 6;
    const size_t xbase = ((size_t)(b * 256 + g * 8)) * 4096;

    float s1 = 0.f, s2 = 0.f;
#pragma unroll
    for (int it = 0; it < 32; it++) {
        const int idx = (it * 256 + tid) * 4;
        const float4 v4 = *(const float4*)(x + xbase + idx);
        s1 += v4.x + v4.y + v4.z + v4.w;
        s2 += v4.x * v4.x + v4.y * v4.y + v4.z * v4.z + v4.w * v4.w;
    }
    __shared__ float red[8];
    float s1w = wave_red_sum(s1);
    float s2w = wave_red_sum(s2);
    if (lane == 0) { red[wid] = s1w; red[4 + wid] = s2w; }
    __syncthreads();
    const float mean = (red[0] + red[1] + red[2] + red[3]) * (1.0f / 32768.0f);
    const float ms   = (red[4] + red[5] + red[6] + red[7]) * (1.0f / 32768.0f);
    const float inv  = rsqrtf(fmaxf(ms - mean * mean, 0.f) + 1e-5f);

    if (tid < 8) {
        const int c = g * 8 + tid;
        const float sc = gw[c] * inv;
        const float sh = gb[c] - mean * sc;
        scsh[b * 256 + c] = make_float2(sc, sh);
    }
}

// ---------------------------------------------------------------------------
// Cast qkv_w fp32 -> bf16; 196608 elems; grid 192, block 256, 4/thread
// ---------------------------------------------------------------------------
__global__ __launch_bounds__(256)
void wcast_kernel(const float* __restrict__ w, __bf16* __restrict__ wb)
{
    const int i = (blockIdx.x * 256 + threadIdx.x) * 4;
    const float4 f = *(const float4*)(w + i);
    bf16x4 t;
    t[0] = (__bf16)f.x; t[1] = (__bf16)f.y; t[2] = (__bf16)f.z; t[3] = (__bf16)f.w;
    *(bf16x4*)(wb + i) = t;
}

// ---------------------------------------------------------------------------
// gemm1: qkv[o][bn] = sum_c wbf[o][c] * gn(x)[c][bn] + bias.
// Grid (6 m-tiles FASTEST, 512 n-tiles); block 256; tile 128x128, BK=32.
// m-fastest: 6 blocks sharing an x-window are dispatch-adjacent -> L2/L3 hit.
// Swizzled 64 B/row LDS: conflict-free b128 staging + fragment reads.
// q-row blocks (m0<256) also emit per-(row, n-tile) softmax partials (M, S).
// ---------------------------------------------------------------------------
__global__ __launch_bounds__(256)
void gemm1_kernel(const __bf16* __restrict__ wbf,
                  const float* __restrict__ x,
                  const float* __restrict__ bias,
                  const float2* __restrict__ scsh,
                  __bf16* __restrict__ qkv,
                  float2* __restrict__ pbuf)
{
    __shared__ __align__(16) char lds_a[8192];
    __shared__ __align__(16) char lds_b[8192];
    __shared__ float2 lscsh[256];
    __shared__ float pm2[2][128], ps2[2][128];

    const int tid  = threadIdx.x;
    const int lane = tid & 63;
    const int wid  = tid >> 6;
    const int quad = lane >> 4;
    const int tcol = lane & 15;
    const int wm   = (wid & 1) * 64;
    const int wn   = (wid >> 1) * 64;
    const int m0   = blockIdx.x * 128;
    const int n0   = blockIdx.y * 128;
    const int b    = n0 >> 12;
    const int nn   = n0 & 4095;

    lscsh[tid] = scsh[b * 256 + tid];

    const int sn  = tid & 127;
    const int sth = tid >> 7;
    const int am  = tid >> 1;
    const int ah  = tid & 1;

    f32x4 acc[4][4];
#pragma unroll
    for (int i = 0; i < 4; i++)
#pragma unroll
        for (int j = 0; j < 4; j++) acc[i][j] = {0.f, 0.f, 0.f, 0.f};

    const float* xcol = x + (size_t)b * 1048576 + nn + sn;
    const int aswz = (am >> 1) & 3;
    const int bswz = (sn >> 1) & 3;

    for (int kt = 0; kt < 256; kt += 32) {
        __syncthreads();
        {   // stage A tile 128x32 (bf16 already)
            const __bf16* asrc = wbf + (m0 + am) * 256 + kt + ah * 16;
            const bf16x8 a0 = *(const bf16x8*)asrc;
            const bf16x8 a1 = *(const bf16x8*)(asrc + 8);
            *(bf16x8*)&lds_a[am * 64 + (((ah * 2)     + aswz) & 3) * 16] = a0;
            *(bf16x8*)&lds_a[am * 64 + (((ah * 2 + 1) + aswz) & 3) * 16] = a1;
        }
        {   // stage B tile 128n x 32c from fp32 x with fused GroupNorm
            const float* xs = xcol + (size_t)(kt + sth * 16) * 4096;
            bf16x8 o0, o1;
#pragma unroll
            for (int j = 0; j < 16; j++) {
                const float2 ss = lscsh[kt + sth * 16 + j];
                const float f = xs[(size_t)j * 4096];
                const __bf16 v = (__bf16)(f * ss.x + ss.y);
                if (j < 8) o0[j] = v; else o1[j - 8] = v;
            }
            *(bf16x8*)&lds_b[sn * 64 + (((sth * 2)     + bswz) & 3) * 16] = o0;
            *(bf16x8*)&lds_b[sn * 64 + (((sth * 2 + 1) + bswz) & 3) * 16] = o1;
        }
        __syncthreads();

        bf16x8 af[4], bfr[4];
#pragma unroll
        for (int mi = 0; mi < 4; mi++) {
            const int m = wm + mi * 16 + tcol;
            af[mi] = *(const bf16x8*)&lds_a[m * 64 + ((quad + ((m >> 1) & 3)) & 3) * 16];
        }
#pragma unroll
        for (int ni = 0; ni < 4; ni++) {
            const int n = wn + ni * 16 + tcol;
            bfr[ni] = *(const bf16x8*)&lds_b[n * 64 + ((quad + ((n >> 1) & 3)) & 3) * 16];
        }
#pragma unroll
        for (int mi = 0; mi < 4; mi++)
#pragma unroll
            for (int ni = 0; ni < 4; ni++)
                acc[mi][ni] = __builtin_amdgcn_mfma_f32_16x16x32_bf16(
                    af[mi], bfr[ni], acc[mi][ni], 0, 0, 0);
    }

    const bool qrows = (m0 < 256);

    // epilogue: C/D layout col = lane&15 (N), row = quad*4 + r (M)
#pragma unroll
    for (int mi = 0; mi < 4; mi++) {
#pragma unroll
        for (int r = 0; r < 4; r++) {
            const int grow = m0 + wm + mi * 16 + quad * 4 + r;
            const float bv = bias[grow];
            float v[4];
#pragma unroll
            for (int ni = 0; ni < 4; ni++) {
                const int gcol = n0 + wn + ni * 16 + tcol;
                const __bf16 ob = (__bf16)(acc[mi][ni][r] + bv);
                qkv[(size_t)grow * 65536 + gcol] = ob;
                v[ni] = (float)ob;
            }
            if (qrows) {   // row-wise partial softmax stats over 64 wave cols
                float mx = fmaxf(fmaxf(v[0], v[1]), fmaxf(v[2], v[3]));
                mx = fmaxf(mx, __shfl_xor(mx, 1, 64));
                mx = fmaxf(mx, __shfl_xor(mx, 2, 64));
                mx = fmaxf(mx, __shfl_xor(mx, 4, 64));
                mx = fmaxf(mx, __shfl_xor(mx, 8, 64));
                float s = __expf(v[0] - mx) + __expf(v[1] - mx)
                        + __expf(v[2] - mx) + __expf(v[3] - mx);
                s += __shfl_xor(s, 1, 64);
                s += __shfl_xor(s, 2, 64);
                s += __shfl_xor(s, 4, 64);
                s += __shfl_xor(s, 8, 64);
                if (tcol == 0) {
                    const int lr = wm + mi * 16 + quad * 4 + r;
                    pm2[wn >> 6][lr] = mx;
                    ps2[wn >> 6][lr] = s;
                }
            }
        }
    }
    if (qrows) {   // combine the two column halves; one partial per row
        __syncthreads();
        if (tid < 128) {
            const float ma = pm2[0][tid], mb = pm2[1][tid];
            const float M = fmaxf(ma, mb);
            const float S = ps2[0][tid] * __expf(ma - M) + ps2[1][tid] * __expf(mb - M);
            pbuf[(size_t)(m0 + tid) * 512 + blockIdx.y] = make_float2(M, S);
        }
    }
}

// ---------------------------------------------------------------------------
// qstats_reduce: fold 32 per-tile partials -> qst[o*16+b] = (M, 1/S)
// grid 16 x 256 threads; one thread per (o,b)
// ---------------------------------------------------------------------------
__global__ __launch_bounds__(256)
void qstats_reduce_kernel(const float2* __restrict__ pbuf, float2* __restrict__ qst)
{
    const int gid = blockIdx.x * 256 + threadIdx.x;   // 0..4095
    const int o = gid >> 4, b = gid & 15;
    const float2* p = pbuf + (size_t)o * 512 + b * 32;
    float M = -INFINITY;
#pragma unroll
    for (int t = 0; t < 32; t++) M = fmaxf(M, p[t].x);
    float S = 0.f;
#pragma unroll
    for (int t = 0; t < 32; t++) S += p[t].y * __expf(p[t].x - M);
    qst[o * 16 + b] = make_float2(M, 1.0f / S);
}

// ---------------------------------------------------------------------------
// ctx[bh][e][d] = sum_n v[e][n] * softmax_d(k)[d][n] via MFMA.
// grid 512 = (bh 64) x (kc 8); block 256 (4 waves, each owns a 32x32 quadrant)
// ---------------------------------------------------------------------------
__global__ __launch_bounds__(256)
void ctx_mfma_kernel(const __bf16* __restrict__ qkv, float* __restrict__ ctx)
{
    const int bh = blockIdx.x >> 3, kc = blockIdx.x & 7;
    const int b = bh >> 2, hh = bh & 3;
    __shared__ __align__(16) __bf16 lk[64 * 72], lv[64 * 72];
    __shared__ float smax[4][64], ssum[4][64];
    const int tid = threadIdx.x;
    const int lane = tid & 63, wid = tid >> 6;
    const int quad = lane >> 4, tcol = lane & 15;
    const int eh = (wid & 1) * 32, dh = (wid >> 1) * 32;
    const int col = tid & 63, dq = tid >> 6;
    const int sd = tid >> 2, snn = (tid & 3) * 16;

    f32x4 acc[2][2];
#pragma unroll
    for (int i = 0; i < 2; i++)
#pragma unroll
        for (int j = 0; j < 2; j++) acc[i][j] = {0.f, 0.f, 0.f, 0.f};

    const size_t kbase = (size_t)(256 + hh * 64) * 65536 + (size_t)b * 4096 + kc * 512;
    const size_t vbase = (size_t)(512 + hh * 64) * 65536 + (size_t)b * 4096 + kc * 512;

    for (int nc = 0; nc < 512; nc += 64) {
        __syncthreads();
        {   // stage k,v tiles [64 ch][64 n], row stride 72
            const __bf16* ks = qkv + kbase + (size_t)sd * 65536 + nc + snn;
            *(bf16x8*)&lk[sd * 72 + snn]     = *(const bf16x8*)ks;
            *(bf16x8*)&lk[sd * 72 + snn + 8] = *(const bf16x8*)(ks + 8);
            const __bf16* vs = qkv + vbase + (size_t)sd * 65536 + nc + snn;
            *(bf16x8*)&lv[sd * 72 + snn]     = *(const bf16x8*)vs;
            *(bf16x8*)&lv[sd * 72 + snn + 8] = *(const bf16x8*)(vs + 8);
        }
        __syncthreads();

        // fused k-softmax over d (full d=64 in tile per column)
        float kvv[16];
        float pm = -INFINITY;
#pragma unroll
        for (int i = 0; i < 16; i++) {
            kvv[i] = (float)lk[(dq * 16 + i) * 72 + col];
            pm = fmaxf(pm, kvv[i]);
        }
        smax[dq][col] = pm;
        __syncthreads();
        const float m = fmaxf(fmaxf(smax[0][col], smax[1][col]),
                              fmaxf(smax[2][col], smax[3][col]));
        float ps = 0.f;
#pragma unroll
        for (int i = 0; i < 16; i++) { kvv[i] = __expf(kvv[i] - m); ps += kvv[i]; }
        ssum[dq][col] = ps;
        __syncthreads();
        const float inv = 1.0f / (ssum[0][col] + ssum[1][col] + ssum[2][col] + ssum[3][col]);
#pragma unroll
        for (int i = 0; i < 16; i++)
            lk[(dq * 16 + i) * 72 + col] = (__bf16)(kvv[i] * inv);
        __syncthreads();

        // MFMA: D[e][d] += sum_n v[e][n] * k_sm[d][n]
#pragma unroll
        for (int k2 = 0; k2 < 64; k2 += 32) {
            bf16x8 af[2], bfr[2];
#pragma unroll
            for (int mi = 0; mi < 2; mi++)
                af[mi] = *(const bf16x8*)&lv[(eh + mi * 16 + tcol) * 72 + k2 + quad * 8];
#pragma unroll
            for (int ni = 0; ni < 2; ni++)
                bfr[ni] = *(const bf16x8*)&lk[(dh + ni * 16 + tcol) * 72 + k2 + quad * 8];
#pragma unroll
            for (int mi = 0; mi < 2; mi++)
#pragma unroll
                for (int ni = 0; ni < 2; ni++)
                    acc[mi][ni] = __builtin_amdgcn_mfma_f32_16x16x32_bf16(
                        af[mi], bfr[ni], acc[mi][ni], 0, 0, 0);
        }
    }
    float* cb = ctx + (size_t)bh * 4096;
#pragma unroll
    for (int mi = 0; mi < 2; mi++)
#pragma unroll
        for (int ni = 0; ni < 2; ni++)
#pragma unroll
            for (int r = 0; r < 4; r++) {
                const int e = eh + mi * 16 + quad * 4 + r;
                const int d = dh + ni * 16 + tcol;
                atomicAdd(&cb[e * 64 + d], acc[mi][ni][r]);
            }
}

// ---------------------------------------------------------------------------
// W2[b][o][h*64+d] = sum_e out_w[o][h*64+e] * ctx[bh][e][d]   (bf16 out)
// grid 64 = (b 16) x (h 4); block 256 (one thread per o)
// ---------------------------------------------------------------------------
__global__ __launch_bounds__(256)
void w2_kernel(const float* __restrict__ ctx, const float* __restrict__ out_w,
               __bf16* __restrict__ w2)
{
    const int bh = blockIdx.x;
    const int b = bh >> 2, hh = bh & 3;
    const int tid = threadIdx.x;

    __shared__ __align__(16) float lctx[4096];
    const float* csrc = ctx + (size_t)bh * 4096;
#pragma unroll
    for (int i = 0; i < 4; i++)
        ((float4*)lctx)[tid + i * 256] = ((const float4*)csrc)[tid + i * 256];
    __syncthreads();

    float acc[64];
#pragma unroll
    for (int d = 0; d < 64; d++) acc[d] = 0.f;

    const float* wrow = out_w + (size_t)tid * 256 + hh * 64;
    for (int e = 0; e < 64; e++) {
        const float w = wrow[e];
#pragma unroll
        for (int d4 = 0; d4 < 64; d4 += 4) {
            const float4 c4 = *(const float4*)&lctx[e * 64 + d4];
            acc[d4 + 0] += w * c4.x;
            acc[d4 + 1] += w * c4.y;
            acc[d4 + 2] += w * c4.z;
            acc[d4 + 3] += w * c4.w;
        }
    }
    __bf16* dst = w2 + (size_t)b * 65536 + (size_t)tid * 256 + hh * 64;
#pragma unroll
    for (int d4 = 0; d4 < 64; d4 += 4) {
        bf16x4 t;
        t[0] = (__bf16)acc[d4 + 0]; t[1] = (__bf16)acc[d4 + 1];
        t[2] = (__bf16)acc[d4 + 2]; t[3] = (__bf16)acc[d4 + 3];
        *(bf16x4*)(dst + d4) = t;
    }
}

// ---------------------------------------------------------------------------
// gemm2: out[b][o][n] = sum_c W2[b][o][c] * softmax_n(q)[c][bn] + out_b + x.
// Same structure as gemm1: grid (2 m-tiles FASTEST, 512 n-tiles), per-kt
// restage, 18 KB LDS, q-softmax fused into B staging via qst.
// ---------------------------------------------------------------------------
__global__ __launch_bounds__(256)
void gemm2_kernel(const __bf16* __restrict__ w2,
                  const __bf16* __restrict__ qkv,
                  const float2* __restrict__ qst,
                  const float* __restrict__ bias,
                  const float* __restrict__ xres,
                  float* __restrict__ out)
{
    __shared__ __align__(16) char lds_a[8192];
    __shared__ __align__(16) char lds_b[8192];
    __shared__ float2 lqst[256];

    const int tid  = threadIdx.x;
    const int lane = tid & 63;
    const int wid  = tid >> 6;
    const int quad = lane >> 4;
    const int tcol = lane & 15;
    const int wm   = (wid & 1) * 64;
    const int wn   = (wid >> 1) * 64;
    const int m0   = blockIdx.x * 128;
    const int n0   = blockIdx.y * 128;
    const int b    = n0 >> 12;
    const int nn   = n0 & 4095;

    lqst[tid] = qst[tid * 16 + b];

    const int sn  = tid & 127;
    const int sth = tid >> 7;
    const int am  = tid >> 1;
    const int ah  = tid & 1;

    f32x4 acc[4][4];
#pragma unroll
    for (int i = 0; i < 4; i++)
#pragma unroll
        for (int j = 0; j < 4; j++) acc[i][j] = {0.f, 0.f, 0.f, 0.f};

    const __bf16* qcol = qkv + (size_t)b * 4096 + nn + sn;
    const __bf16* abase = w2 + (size_t)b * 65536;
    const int aswz = (am >> 1) & 3;
    const int bswz = (sn >> 1) & 3;

    for (int kt = 0; kt < 256; kt += 32) {
        __syncthreads();
        {   // stage A tile 128x32 from W2[b]
            const __bf16* asrc = abase + (m0 + am) * 256 + kt + ah * 16;
            const bf16x8 a0 = *(const bf16x8*)asrc;
            const bf16x8 a1 = *(const bf16x8*)(asrc + 8);
            *(bf16x8*)&lds_a[am * 64 + (((ah * 2)     + aswz) & 3) * 16] = a0;
            *(bf16x8*)&lds_a[am * 64 + (((ah * 2 + 1) + aswz) & 3) * 16] = a1;
        }
        {   // stage B tile 128n x 32c: softmax(q) on the fly
            const __bf16* qs = qcol + (size_t)(kt + sth * 16) * 65536;
            bf16x8 o0, o1;
#pragma unroll
            for (int j = 0; j < 16; j++) {
                const float2 qq = lqst[kt + sth * 16 + j];
                const float f = (float)qs[(size_t)j * 65536];
                const __bf16 v = (__bf16)(__expf(f - qq.x) * qq.y);
                if (j < 8) o0[j] = v; else o1[j - 8] = v;
            }
            *(bf16x8*)&lds_b[sn * 64 + (((sth * 2)     + bswz) & 3) * 16] = o0;
            *(bf16x8*)&lds_b[sn * 64 + (((sth * 2 + 1) + bswz) & 3) * 16] = o1;
        }
        __syncthreads();

        bf16x8 af[4], bfr[4];
#pragma unroll
        for (int mi = 0; mi < 4; mi++) {
            const int m = wm + mi * 16 + tcol;
            af[mi] = *(const bf16x8*)&lds_a[m * 64 + ((quad + ((m >> 1) & 3)) & 3) * 16];
        }
#pragma unroll
        for (int ni = 0; ni < 4; ni++) {
            const int n = wn + ni * 16 + tcol;
            bfr[ni] = *(const bf16x8*)&lds_b[n * 64 + ((quad + ((n >> 1) & 3)) & 3) * 16];
        }
#pragma unroll
        for (int mi = 0; mi < 4; mi++)
#pragma unroll
            for (int ni = 0; ni < 4; ni++)
                acc[mi][ni] = __builtin_amdgcn_mfma_f32_16x16x32_bf16(
                    af[mi], bfr[ni], acc[mi][ni], 0, 0, 0);
    }

#pragma unroll
    for (int mi = 0; mi < 4; mi++) {
#pragma unroll
        for (int r = 0; r < 4; r++) {
            const int grow = m0 + wm + mi * 16 + quad * 4 + r;
            const float bv = bias[grow];
#pragma unroll
            for (int ni = 0; ni < 4; ni++) {
                const int n = nn + wn + ni * 16 + tcol;
                const size_t oidx = ((size_t)(b * 256 + grow)) * 4096 + n;
                out[oidx] = acc[mi][ni][r] + bv + xres[oidx];
            }
        }
    }
}

// ---------------------------------------------------------------------------
extern "C" void kernel_launch(void* const* d_in, const int* in_sizes, int n_in,
                              void* d_out, int out_size, void* d_ws, size_t ws_size,
                              hipStream_t stream)
{
    const float* x     = (const float*)d_in[0];
    const float* gn_w  = (const float*)d_in[1];
    const float* gn_b  = (const float*)d_in[2];
    const float* qkv_w = (const float*)d_in[3];
    const float* qkv_b = (const float*)d_in[4];
    const float* out_w = (const float*)d_in[5];
    const float* out_b = (const float*)d_in[6];
    float* out = (float*)d_out;

    char* ws = (char*)d_ws;
    __bf16* qkv  = (__bf16*)ws;                                   // 100,663,296 B
    float*  ctx  = (float*)(ws + (size_t)100663296);              //   1,048,576 B
    float2* scsh = (float2*)(ws + (size_t)101711872);             //      32,768 B
    float2* qst  = (float2*)(ws + (size_t)101744640);             //      32,768 B
    __bf16* wbf  = (__bf16*)(ws + (size_t)101777408);             //     393,216 B
    float2* pbuf = (float2*)(ws + (size_t)102170624);             //   1,048,576 B
    __bf16* w2   = qkv + (size_t)256 * 65536;                     // dead k rows

    hipMemsetAsync(ctx, 0, 262144 * sizeof(float), stream);
    gn_stats_kernel<<<512, 256, 0, stream>>>(x, gn_w, gn_b, scsh);
    wcast_kernel<<<192, 256, 0, stream>>>(qkv_w, wbf);
    gemm1_kernel<<<dim3(6, 512), 256, 0, stream>>>(wbf, x, qkv_b, scsh, qkv, pbuf);
    qstats_reduce_kernel<<<16, 256, 0, stream>>>(pbuf, qst);
    ctx_mfma_kernel<<<512, 256, 0, stream>>>(qkv, ctx);
    w2_kernel<<<64, 256, 0, stream>>>(ctx, out_w, w2);
    gemm2_kernel<<<dim3(2, 512), 256, 0, stream>>>(w2, qkv, qst, out_b, x, out);
}